// Round 1
// 305.952 us; speedup vs baseline: 1.0693x; 1.0693x over previous
//
#include <hip/hip_runtime.h>
#include <hip/hip_bf16.h>

// Problem constants
#define B_ROWS 16384
#define K_DIM  1024
#define N_INT  1023
#define N_OUT  1000

using s8vec = __attribute__((ext_vector_type(8))) short;   // 8 bf16 (4 VGPRs) MFMA operand
using f32x4 = __attribute__((ext_vector_type(4))) float;   // MFMA accumulator

// Workspace layout (bytes). Total ~105 MB.
static const size_t OFF_XB   = 0;                        // bf16 [16384*1024]
static const size_t OFF_W1   = OFF_XB   + 33554432;      // bf16 [1024*1024] (row 1023 = 0)
static const size_t OFF_BIAS = OFF_W1   + 2097152;       // f32  [1024]
static const size_t OFF_PROB = OFF_BIAS + 4096;          // bf16 [16384*1024]; node j at col j+1
static const size_t OFF_PATH = OFF_PROB + 33554432;      // bf16 [16384*1024]
static const size_t OFF_W2   = OFF_PATH + 33554432;      // bf16 [1024*1024] (rows >=1000 = 0)
static const size_t OFF_SG   = OFF_W2   + 2097152;       // f32  [4096]: S1 at [node], S2 at [2048+node]

__device__ __forceinline__ float b2f(ushort u) {
  return __uint_as_float(((unsigned)u) << 16);
}
__device__ __forceinline__ float blo(unsigned u) { return __uint_as_float(u << 16); }
__device__ __forceinline__ float bhi(unsigned u) { return __uint_as_float(u & 0xffff0000u); }
__device__ __forceinline__ ushort f2b(float f) {
  unsigned u = __float_as_uint(f);
  u = u + 0x7FFFu + ((u >> 16) & 1u);   // RNE
  return (ushort)(u >> 16);
}

// async global->LDS, 16B per lane; LDS dest is wave-uniform base + lane*16
__device__ __forceinline__ void load_lds16(const ushort* g, ushort* l) {
  __builtin_amdgcn_global_load_lds((const __attribute__((address_space(1))) void*)g,
                                   (__attribute__((address_space(3))) void*)l,
                                   16, 0, 0);
}

// ---------------- converts ----------------
__global__ __launch_bounds__(256) void cvt_x(const float4* __restrict__ X,
                                             ushort4* __restrict__ O) {
  const int i = blockIdx.x * 256 + threadIdx.x;
  const float4 v = X[i];
  ushort4 o;
  o.x = f2b(v.x); o.y = f2b(v.y); o.z = f2b(v.z); o.w = f2b(v.w);
  O[i] = o;
}

// fused weight converts: idx<2^20 -> W_internal (+bias), else -> W_leaf
__global__ __launch_bounds__(256) void cvt_w(const float* __restrict__ Wi,
                                             const float* __restrict__ Wl,
                                             ushort* __restrict__ W1,
                                             ushort* __restrict__ W2,
                                             float* __restrict__ bias) {
  const int idx = blockIdx.x * 256 + threadIdx.x;   // [0, 2*2^20)
  if (idx < (1 << 20)) {
    const int n = idx >> 10, k = idx & 1023;
    const float v = (n < N_INT) ? Wi[n * 1025 + 1 + k] : 0.f;
    W1[idx] = f2b(v);
    if (k == 0) bias[n] = (n < N_INT) ? Wi[n * 1025] : 0.f;
  } else {
    const int j = idx - (1 << 20);
    const int n = j >> 10, k = j & 1023;
    const float v = (n < N_OUT) ? Wl[n * 1024 + k] : 0.f;
    W2[j] = f2b(v);
  }
}

// ---------------- GEMM: C = A[M,K] * Bm[N,K]^T, 128x128 tile, 4 waves ----------------
// m97 structure: global_load_lds width-16 staging (no VGPR round-trip), single
// LDS buffer, 2 barriers/K-step. LDS stores chunk-swizzled (slot = q ^ ((row>>1)&3)):
// the swizzle is applied on the GLOBAL source address (global_load_lds dest must
// stay linear) and on the ds_read address -- spreads the 64B-stride b128 fragment
// reads over all 8 bank slots (2 lanes/slot = conflict-free, was 8-way).
// Grid is (bm=128 fast, bn=8): linear id % 8 == bm % 8, so all 8 bn-blocks sharing
// an A strip land on ONE XCD's L2 (was: 8 different XCDs -> 3.7x A overfetch).
// MODE 0: sigmoid(acc + bias[n]) -> bf16 probs, node gc stored at column gc+1
// MODE 1: store f32 to out [M,1000] (guard n<1000)
template <int MODE>
__global__ __launch_bounds__(256, 4) void gemm_bt(const ushort* __restrict__ A,
                                                  const ushort* __restrict__ Bm,
                                                  const float* __restrict__ bias,
                                                  void* __restrict__ outp) {
  __shared__ ushort As[4096];   // [128 rows][32 k] bf16, chunk-swizzled
  __shared__ ushort Bs[4096];
  const int tid = threadIdx.x;
  const int bm = blockIdx.x, bn = blockIdx.y;   // TRANSPOSED grid for XCD locality
  const int lane = tid & 63, wv = tid >> 6;
  const int wm = wv >> 1, wn = wv & 1;
  const int m16 = lane & 15, q = lane >> 4;
  const int qs = q ^ ((m16 >> 1) & 3);          // read-side chunk swizzle (per-lane const)

  // staging: thread tid fills LDS bytes [tid*16, +16) of each 4KB half-tile.
  // row r0 = tid>>2 (call 1) / r0+64 (call 2); stored slot tid&3 must hold
  // logical chunk (tid&3) ^ ((r0>>1)&3)  [(r0+64)>>1 has same &3 -> one qsw]
  const int r0 = tid >> 2;
  const int qsw = (tid & 3) ^ ((r0 >> 1) & 3);
  const ushort* aG = A  + (size_t)(bm * 128 + r0) * 1024 + qsw * 8;
  const ushort* bG = Bm + (size_t)(bn * 128 + r0) * 1024 + qsw * 8;
  ushort* AsW = As + wv * 512;    // wave-uniform LDS base (1KB per wave per call)
  ushort* BsW = Bs + wv * 512;

  f32x4 acc[4][4] = {};

  for (int k0 = 0; k0 < 1024; k0 += 32) {
    if (k0) __syncthreads();              // prior iter's ds_reads done before overwrite
    load_lds16(aG + k0, AsW);             // rows 0..63
    load_lds16(aG + 65536 + k0, AsW + 2048);  // rows 64..127
    load_lds16(bG + k0, BsW);
    load_lds16(bG + 65536 + k0, BsW + 2048);
    __syncthreads();                      // vmcnt drain -> LDS tile valid

    s8vec af[4], bfv[4];
#pragma unroll
    for (int i = 0; i < 4; ++i)
      af[i] = *(const s8vec*)(As + (wm * 64 + i * 16 + m16) * 32 + qs * 8);
#pragma unroll
    for (int j = 0; j < 4; ++j)
      bfv[j] = *(const s8vec*)(Bs + (wn * 64 + j * 16 + m16) * 32 + qs * 8);
#pragma unroll
    for (int i = 0; i < 4; ++i)
#pragma unroll
      for (int j = 0; j < 4; ++j)
        acc[i][j] = __builtin_amdgcn_mfma_f32_16x16x32_bf16(af[i], bfv[j], acc[i][j], 0, 0, 0);
  }

  // C/D layout: col = lane&15, row = (lane>>4)*4 + r   [measured: learn_hip m89/m91]
  if (MODE == 0) {
    ushort* P = (ushort*)outp;
#pragma unroll
    for (int i = 0; i < 4; ++i)
#pragma unroll
      for (int r = 0; r < 4; ++r) {
        const int gr = bm * 128 + wm * 64 + i * 16 + q * 4 + r;
#pragma unroll
        for (int j = 0; j < 4; ++j) {
          const int gc = bn * 128 + wn * 64 + j * 16 + m16;
          const float z = acc[i][j][r] + bias[gc];
          const float p = 1.f / (1.f + expf(-z));
          if (gc < N_INT) P[(size_t)gr * 1024 + gc + 1] = f2b(p);  // +1 layer-aligned layout
        }
      }
  } else {
    float* O = (float*)outp;
#pragma unroll
    for (int i = 0; i < 4; ++i)
#pragma unroll
      for (int r = 0; r < 4; ++r) {
        const int gr = bm * 128 + wm * 64 + i * 16 + q * 4 + r;
#pragma unroll
        for (int j = 0; j < 4; ++j) {
          const int gc = bn * 128 + wn * 64 + j * 16 + m16;
          if (gc < N_OUT) O[(size_t)gr * 1000 + gc] = acc[i][j][r];
        }
      }
  }
}

// ---------------- tree: wave-per-4-rows path products + S1/S2 reductions ----------------
// Prob layout: node j of layer ell at prow[(1<<ell) + j]  (aligned vector loads).
// Latency-bound fix vs previous version: (a) layers 0..5 served from ONE coalesced
// 2B/lane load of prow[0..63] + __shfl (register crossbar) instead of 6 dependent
// scalar loads per row; (b) ALL 4 rows' bulk loads hoisted to the top so ~20
// loads/wave are in flight while rows compute.
__global__ __launch_bounds__(256) void tree_kernel(const ushort* __restrict__ probs,
                                                   ushort* __restrict__ path,
                                                   float* __restrict__ Sg) {
  __shared__ float Ss[4096];    // [0..2047]=S1 by node id, [2048..4095]=S2
  for (int i = threadIdx.x; i < 4096; i += 256) Ss[i] = 0.f;
  __syncthreads();
  const int lane = threadIdx.x & 63;
  const int gw = blockIdx.x * 4 + (threadIdx.x >> 6);   // 4096 waves total

  float at1[6] = {}, at2[6] = {};     // layers 0..5
  float ae1[30] = {}, ae2[30] = {};   // layers 6..9, lanes<32: 2+4+8+16 slots

  // ---- load phase: all rows, all in flight ----
  ushort h4[4], p6a[4]; uint p7a[4]; uint2 p8a[4]; uint4 p9a[4];
#pragma unroll
  for (int rr = 0; rr < 4; ++rr) {
    const ushort* prow = probs + (size_t)(gw * 4 + rr) * 1024;
    h4[rr]  = prow[lane];                           // cols 0..63 (layers 0..5; col 0 unused)
    p6a[rr] = prow[64 + lane];
    p7a[rr] = *(const uint*)(prow + 128 + 2 * lane);
    p8a[rr] = *(const uint2*)(prow + 256 + 4 * lane);
    p9a[rr] = *(const uint4*)(prow + 512 + 8 * lane);
  }

#pragma unroll
  for (int rr = 0; rr < 4; ++rr) {
    const int r = gw * 4 + rr;
    const int hh = (int)h4[rr];
    const ushort p6 = p6a[rr];
    const uint   p7 = p7a[rr];
    const uint2  p8 = p8a[rr];
    const uint4  p9 = p9a[rr];

    // prefix chain down to the size-64 layer via shuffles; lane = entry index there
    float v = 1.f;
#pragma unroll
    for (int t = 1; t <= 6; ++t) {
      const int ell = t - 1;
      const int e = lane >> (6 - t);
      const float p = b2f((ushort)__shfl(hh, (1 << ell) + (e >> 1)));   // idx <= 63
      v *= (e & 1) ? (1.f - p) : p;
      // shfl hoisted out of the divergent if (all lanes participate); clamp idx
      const float pj = b2f((ushort)__shfl(hh, ((1 << ell) + e) & 63));
      if (((lane & ((1 << (6 - t)) - 1)) == 0) && (e < (1 << ell))) {
        at1[ell] += v;
        at2[ell] += pj * v;
      }
    }

    float w[16];
    // ---- layer 6 (s=1): parent prob = p6 (node lane) ----
    {
      const float p = b2f(p6);
      w[1] = v * (1.f - p); w[0] = v * p;
    }
    {  // acc layer 6: lanes<32 own entries 2l,2l+1; pj from lanes 2l,2l+1
      const int j0 = __shfl((int)p6, 2 * lane);
      const int j1 = __shfl((int)p6, 2 * lane + 1);
      if (lane < 32) {
        ae1[0] += w[0]; ae2[0] += b2f((ushort)j0) * w[0];
        ae1[1] += w[1]; ae2[1] += b2f((ushort)j1) * w[1];
      }
    }
    // ---- layer 7 (s=2): probs nodes 2l,2l+1 = p7 lo/hi ----
    {
      const float pA = blo(p7), pB = bhi(p7);
      w[3] = w[1] * (1.f - pB); w[2] = w[1] * pB;
      w[1] = w[0] * (1.f - pA); w[0] = w[0] * pA;
    }
    {
      const uint ua = (uint)__shfl((int)p7, 2 * lane);
      const uint ub = (uint)__shfl((int)p7, 2 * lane + 1);
      if (lane < 32) {
        ae1[2] += w[0]; ae2[2] += blo(ua) * w[0];
        ae1[3] += w[1]; ae2[3] += bhi(ua) * w[1];
        ae1[4] += w[2]; ae2[4] += blo(ub) * w[2];
        ae1[5] += w[3]; ae2[5] += bhi(ub) * w[3];
      }
    }
    // ---- layer 8 (s=4): probs nodes 4l..4l+3 = p8 ----
    {
      const float pv[4] = { blo(p8.x), bhi(p8.x), blo(p8.y), bhi(p8.y) };
#pragma unroll
      for (int i = 3; i >= 0; --i) {
        w[2 * i + 1] = w[i] * (1.f - pv[i]);
        w[2 * i]     = w[i] * pv[i];
      }
    }
    {
      const uint u0 = (uint)__shfl((int)p8.x, 2 * lane);
      const uint u1 = (uint)__shfl((int)p8.y, 2 * lane);
      const uint u2 = (uint)__shfl((int)p8.x, 2 * lane + 1);
      const uint u3 = (uint)__shfl((int)p8.y, 2 * lane + 1);
      if (lane < 32) {
        ae1[6]  += w[0]; ae2[6]  += blo(u0) * w[0];
        ae1[7]  += w[1]; ae2[7]  += bhi(u0) * w[1];
        ae1[8]  += w[2]; ae2[8]  += blo(u1) * w[2];
        ae1[9]  += w[3]; ae2[9]  += bhi(u1) * w[3];
        ae1[10] += w[4]; ae2[10] += blo(u2) * w[4];
        ae1[11] += w[5]; ae2[11] += bhi(u2) * w[5];
        ae1[12] += w[6]; ae2[12] += blo(u3) * w[6];
        ae1[13] += w[7]; ae2[13] += bhi(u3) * w[7];
      }
    }
    // ---- layer 9 (s=8): probs nodes 8l..8l+7 = p9 ----
    {
      const uint pv[4] = { p9.x, p9.y, p9.z, p9.w };
#pragma unroll
      for (int i = 7; i >= 0; --i) {
        const float p = (i & 1) ? bhi(pv[i >> 1]) : blo(pv[i >> 1]);
        w[2 * i + 1] = w[i] * (1.f - p);
        w[2 * i]     = w[i] * p;
      }
    }
    {
      uint s_[8];
      s_[0] = (uint)__shfl((int)p9.x, 2 * lane);
      s_[1] = (uint)__shfl((int)p9.y, 2 * lane);
      s_[2] = (uint)__shfl((int)p9.z, 2 * lane);
      s_[3] = (uint)__shfl((int)p9.w, 2 * lane);
      s_[4] = (uint)__shfl((int)p9.x, 2 * lane + 1);
      s_[5] = (uint)__shfl((int)p9.y, 2 * lane + 1);
      s_[6] = (uint)__shfl((int)p9.z, 2 * lane + 1);
      s_[7] = (uint)__shfl((int)p9.w, 2 * lane + 1);
      if (lane < 32) {
#pragma unroll
        for (int i = 0; i < 16; ++i) {
          const uint u = s_[i >> 1];
          const float pj = (i & 1) ? bhi(u) : blo(u);
          ae1[14 + i] += w[i]; ae2[14 + i] += pj * w[i];
        }
      }
    }
    // store 16 leaves (32B per lane, two 16B stores)
    union { ushort u[16]; uint4 q4[2]; } pk;
#pragma unroll
    for (int i = 0; i < 16; ++i) pk.u[i] = f2b(w[i]);
    uint4* dst = (uint4*)(path + (size_t)r * 1024 + lane * 16);
    dst[0] = pk.q4[0];
    dst[1] = pk.q4[1];
  }

  // merge register accumulators -> LDS (node id = (1<<ell)-1 + j)
#pragma unroll
  for (int t = 1; t <= 6; ++t) {
    const int ell = t - 1;
    const int e = lane >> (6 - t);
    if (((lane & ((1 << (6 - t)) - 1)) == 0) && (e < (1 << ell))) {
      const int node = (1 << ell) - 1 + e;
      atomicAdd(&Ss[node], at1[ell]);
      atomicAdd(&Ss[2048 + node], at2[ell]);
    }
  }
  if (lane < 32) {
#pragma unroll
    for (int ell = 6; ell <= 9; ++ell) {
      const int s = 1 << (ell - 6);
      const int pb = (1 << ell) - 1;
      const int base = 2 * s - 2;
#pragma unroll
      for (int i = 0; i < 2 * s; ++i) {
        const int node = pb + 2 * s * lane + i;
        atomicAdd(&Ss[node], ae1[base + i]);
        atomicAdd(&Ss[2048 + node], ae2[base + i]);
      }
    }
  }
  __syncthreads();
  // one global atomic per node per block (1024 blocks x 2046 atomics)
  for (int i = threadIdx.x; i < 1023; i += 256) {
    atomicAdd(&Sg[i], Ss[i]);
    atomicAdd(&Sg[2048 + i], Ss[2048 + i]);
  }
}

// ---------------- finalize: alphas + log-regularizer ----------------
__global__ __launch_bounds__(1024) void finalize_kernel(const float* __restrict__ Sg,
                                                        float* __restrict__ outreg) {
  const int tid = threadIdx.x;
  double val = 0.0;
  if (tid < 1023) {
    const int ell = 31 - __clz(tid + 1);           // node tid is in layer ell
    const double s1 = (double)Sg[tid];
    const double s2 = (double)Sg[2048 + tid];
    const double den = s1 + 1e-8;
    const double a0 = s2 / den;                    // alpha for even child
    const double a1 = (s1 - s2) / den;             // alpha for odd child
    const double f = 1e-3 * (1.0 / (double)(1 << ell));
    val = -0.5 * f * (log(a0) + log(1.0 - a0) + log(a1) + log(1.0 - a1));
  }
#pragma unroll
  for (int o = 32; o > 0; o >>= 1) val += __shfl_down(val, o, 64);
  __shared__ double partd[16];
  if ((tid & 63) == 0) partd[tid >> 6] = val;
  __syncthreads();
  if (tid == 0) {
    double t = 0.0;
    for (int i = 0; i < 16; ++i) t += partd[i];
    outreg[0] = (float)t;
  }
}

extern "C" void kernel_launch(void* const* d_in, const int* in_sizes, int n_in,
                              void* d_out, int out_size, void* d_ws, size_t ws_size,
                              hipStream_t stream) {
  const float* X     = (const float*)d_in[0];   // [16384,1024]
  const float* Wint  = (const float*)d_in[1];   // [1023,1025]
  const float* Wleaf = (const float*)d_in[2];   // [1000,1024]
  float* out = (float*)d_out;                   // [16384*1000] preds + [1] reg
  char* ws = (char*)d_ws;                       // needs ~105 MB

  ushort* Xb   = (ushort*)(ws + OFF_XB);
  ushort* W1   = (ushort*)(ws + OFF_W1);
  float*  bias = (float*)(ws + OFF_BIAS);
  ushort* prob = (ushort*)(ws + OFF_PROB);
  ushort* path = (ushort*)(ws + OFF_PATH);
  ushort* W2   = (ushort*)(ws + OFF_W2);
  float*  Sg   = (float*)(ws + OFF_SG);

  (void)hipMemsetAsync(ws + OFF_SG, 0, 16384, stream);  // zero Sg
  cvt_x<<<16384, 256, 0, stream>>>((const float4*)X, (ushort4*)Xb);
  cvt_w<<<8192, 256, 0, stream>>>(Wint, Wleaf, W1, W2, bias);
  gemm_bt<0><<<dim3(128, 8), 256, 0, stream>>>(Xb, W1, bias, (void*)prob);
  tree_kernel<<<1024, 256, 0, stream>>>(prob, path, Sg);
  gemm_bt<1><<<dim3(128, 8), 256, 0, stream>>>(path, W2, nullptr, (void*)out);
  finalize_kernel<<<1, 1024, 0, stream>>>(Sg, out + (size_t)B_ROWS * N_OUT);
}